// Round 8
// baseline (347.335 us; speedup 1.0000x reference)
//
#include <hip/hip_runtime.h>

#define T_HORIZON 50
#define NU 4
#define NY 4
#define KH 32
#define BPB 64                    // batch elements per block (each wave: all 64)

typedef float v2f __attribute__((ext_vector_type(2)));

// Packed fp32 FMA, weight pair in SGPRs (src0), forced by inline asm.
// D = w*x + c per component; per-element IEEE-identical to scalar fmaf.
__device__ __forceinline__ v2f pk_fma_sw(v2f w, v2f x, v2f c) {
    v2f d;
    asm("v_pk_fma_f32 %0, %1, %2, %3" : "=&v"(d) : "s"(w), "v"(x), "v"(c));
    return d;
}

#define TANH_SCALE 2.88539008177792681472f

// Stage transposed weights into d_ws: ws[jg][i][k] = W_all[i][jg + 4k]
// i=0..7: Wh rows; i=8: bh; i=9: wor. 4*10*8 = 320 floats.
__global__ void stage_weights(const float* __restrict__ Whg,
                              const float* __restrict__ bhg,
                              const float* __restrict__ Wog,
                              float* __restrict__ ws) {
    int idx = threadIdx.x;
    if (idx < 320) {
        int jg = idx / 80, r = idx % 80, i = r / 8, k = r % 8;
        int j = jg + 4 * k;
        float v = (i < 8) ? Whg[i * KH + j] : (i == 8 ? bhg[j] : Wog[j]);
        ws[idx] = v;
    }
}

__global__ __launch_bounds__(256, 6) void rollout_kernel(
    const float* __restrict__ u,    // (B, 50, 4)
    const float* __restrict__ y0g,  // (B, 4)
    const float* __restrict__ bog,  // (1)
    const float* __restrict__ wsW,  // (4, 10, 8) staged
    float* __restrict__ out)        // (B, 50, 1)
{
    __shared__ __align__(16) float sOut[BPB * T_HORIZON];  // [b_local][t]
    __shared__ float sRed[2][4][BPB];                      // dbuf class partials

    const int tid  = threadIdx.x;
    const int lane = tid & 63;
    const int jg = __builtin_amdgcn_readfirstlane(tid >> 6);

    const float* wb = wsW + jg * 80;   // uniform base
    // Wave-uniform weight pairs -> SGPR pairs (consumed by pk_fma src0).
    v2f wh2[8][4], wor2[4];
#pragma unroll
    for (int i = 0; i < 8; ++i)
#pragma unroll
        for (int p = 0; p < 4; ++p)
            wh2[i][p] = *(const v2f*)(wb + i * 8 + 2 * p);
#pragma unroll
    for (int p = 0; p < 4; ++p)
        wor2[p] = *(const v2f*)(wb + 9 * 8 + 2 * p);
    const float bor = bog[0];          // uniform -> SGPR

    // bh: VGPR operand of the first pk_fma (src2). 32-bit pins (safe, r6).
    float bhs[8];
#pragma unroll
    for (int k = 0; k < 8; ++k) bhs[k] = wb[8 * 8 + k];
#pragma unroll
    for (int k = 0; k < 8; ++k) asm volatile("" : "+v"(bhs[k]));
    v2f bh2[4];
#pragma unroll
    for (int p = 0; p < 4; ++p) bh2[p] = v2f{bhs[2 * p], bhs[2 * p + 1]};

    const v2f scale2 = {TANH_SCALE, TANH_SCALE};
    const v2f one2   = {1.0f, 1.0f};
    const v2f ntwo2  = {-2.0f, -2.0f};

    const int b = blockIdx.x * BPB + lane;
    const float4* ub = (const float4*)(u + (size_t)b * T_HORIZON * NU);
    float4 yv = *(const float4*)(y0g + (size_t)b * NY);
    // y-state maintained as broadcast pairs (both halves equal).
    v2f py1 = {yv.x, yv.x}, py2 = {yv.y, yv.y}, py3 = {yv.z, yv.z}, py4 = {yv.w, yv.w};

    float4 un = ub[0];
    for (int t = 0; t < T_HORIZON; ++t) {
        float4 uc = un;
        if (t + 1 < T_HORIZON) un = ub[t + 1];

        v2f ux = {uc.x, uc.x}, uy = {uc.y, uc.y}, uz = {uc.z, uc.z}, uw = {uc.w, uc.w};

        float pcls = 0.0f;
#pragma unroll
        for (int p = 0; p < 4; ++p) {
            // identical element order to rounds 2/4/7: bh, u0..u3, y1..y4
            v2f a = pk_fma_sw(wh2[0][p], ux, bh2[p]);
            a = pk_fma_sw(wh2[1][p], uy,  a);
            a = pk_fma_sw(wh2[2][p], uz,  a);
            a = pk_fma_sw(wh2[3][p], uw,  a);
            a = pk_fma_sw(wh2[4][p], py1, a);
            a = pk_fma_sw(wh2[5][p], py2, a);
            a = pk_fma_sw(wh2[6][p], py3, a);
            a = pk_fma_sw(wh2[7][p], py4, a);

            // tanh cluster, per-element identical to round 7:
            v2f s = a * scale2;
            float e0 = __builtin_amdgcn_exp2f(s.x);
            float e1 = __builtin_amdgcn_exp2f(s.y);
            v2f ep = v2f{e0, e1} + one2;
            v2f r  = {__builtin_amdgcn_rcpf(ep.x), __builtin_amdgcn_rcpf(ep.y)};
            v2f th = __builtin_elementwise_fma(ntwo2, r, one2);
            v2f m  = th * wor2[p];
            pcls += m.x;   // k=2p   (j = jg+8p)
            pcls += m.y;   // k=2p+1 (j = jg+8p+4)
        }

        // Cross-wave class reduce: double-buffered, ONE barrier per step.
        const int buf = t & 1;
        sRed[buf][jg][lane] = pcls;
        __syncthreads();
        float c0 = sRed[buf][0][lane];
        float c1 = sRed[buf][1][lane];
        float c2 = sRed[buf][2][lane];
        float c3 = sRed[buf][3][lane];
        float partial = (c0 + c1) + (c2 + c3);
        float pred = bor + partial;

        if (jg == 0) sOut[lane * T_HORIZON + t] = pred;

        py4 = py3; py3 = py2; py2 = py1;
        py1 = v2f{pred, pred};
    }
    __syncthreads();

    // Coalesced flush: block's out region is contiguous 64*50 floats.
    const float4* s4 = (const float4*)sOut;
    float4* o4 = (float4*)(out + (size_t)blockIdx.x * BPB * T_HORIZON);
#pragma unroll
    for (int k = 0; k < 4; ++k) {
        int idx = k * 256 + tid;
        if (idx < (BPB * T_HORIZON) / 4) o4[idx] = s4[idx];
    }
}

extern "C" void kernel_launch(void* const* d_in, const int* in_sizes, int n_in,
                              void* d_out, int out_size, void* d_ws, size_t ws_size,
                              hipStream_t stream) {
    const float* u   = (const float*)d_in[0];
    const float* y0g = (const float*)d_in[1];
    const float* Whg = (const float*)d_in[2];
    const float* bhg = (const float*)d_in[3];
    const float* Wog = (const float*)d_in[4];
    const float* bog = (const float*)d_in[5];
    float* out = (float*)d_out;
    float* ws  = (float*)d_ws;    // 320 floats staged weights

    stage_weights<<<1, 320, 0, stream>>>(Whg, bhg, Wog, ws);

    const int B = in_sizes[1] / NY;          // 524288
    dim3 grid(B / BPB), block(256);
    rollout_kernel<<<grid, block, 0, stream>>>(u, y0g, bog, ws, out);
}